// Round 2
// baseline (589.417 us; speedup 1.0000x reference)
//
#include <hip/hip_runtime.h>

#define BATCH 32
#define SEQL 4096
#define DIM 768
#define D4 192           // DIM / 4 float4-chunks
#define WIN 32
#define NPOS 65          // 2*WIN + 1
#define SLICES 5         // position slices per block
#define PERSLICE 13      // SLICES * PERSLICE == NPOS
#define NT (SLICES * D4) // 960 threads = 15 waves
#define LN_EPS 1e-5f

// One block per batch: gather window diff, masked mean, LayerNorm. No d_ws.
__global__ __launch_bounds__(NT) void fused_vdp_kernel(
    const float4* __restrict__ refv, const float4* __restrict__ altv,
    const int* __restrict__ pos, const float4* __restrict__ gammav,
    const float4* __restrict__ betav, float4* __restrict__ outv) {
  const int b = blockIdx.x;
  const int tid = threadIdx.x;
  const int slice = tid / D4;   // 0..4
  const int d4 = tid % D4;      // 0..191

  const int p = pos[b];
  const int p0 = p - WIN;
  const int lo = p0 > 0 ? p0 : 0;
  const int hi = (p + WIN) < (SEQL - 1) ? (p + WIN) : (SEQL - 1);
  const float inv_cnt = 1.f / (float)(hi - lo + 1);

  // Each slice handles positions p0 + slice + 5*k, k = 0..12.
  float4 acc = make_float4(0.f, 0.f, 0.f, 0.f);
#pragma unroll
  for (int k = 0; k < PERSLICE; ++k) {
    const int q = p0 + slice + SLICES * k;
    if (q >= 0 && q < SEQL) {
      const size_t off = ((size_t)b * SEQL + q) * D4 + d4;
      const float4 a = altv[off];
      const float4 r = refv[off];
      acc.x += a.x - r.x;
      acc.y += a.y - r.y;
      acc.z += a.z - r.z;
      acc.w += a.w - r.w;
    }
  }

  __shared__ float4 part[SLICES][D4];
  __shared__ float sh[6];
  part[slice][d4] = acc;
  __syncthreads();

  if (tid < D4) {
    float4 s = part[0][tid];
#pragma unroll
    for (int j = 1; j < SLICES; ++j) {
      const float4 v = part[j][tid];
      s.x += v.x; s.y += v.y; s.z += v.z; s.w += v.w;
    }
    s.x *= inv_cnt; s.y *= inv_cnt; s.z *= inv_cnt; s.w *= inv_cnt;

    float lsum = s.x + s.y + s.z + s.w;
    float lsq  = s.x * s.x + s.y * s.y + s.z * s.z + s.w * s.w;
#pragma unroll
    for (int off = 32; off > 0; off >>= 1) {
      lsum += __shfl_down(lsum, off);
      lsq  += __shfl_down(lsq, off);
    }
    const int wave = tid >> 6;   // 0..2
    if ((tid & 63) == 0) {
      sh[wave] = lsum;
      sh[3 + wave] = lsq;
    }
    // stash s back for after the barrier
    part[0][tid] = s;
  }
  __syncthreads();

  if (tid < D4) {
    const float4 s = part[0][tid];
    const float tot   = sh[0] + sh[1] + sh[2];
    const float totsq = sh[3] + sh[4] + sh[5];
    const float mu  = tot * (1.f / (float)DIM);
    const float var = totsq * (1.f / (float)DIM) - mu * mu;
    const float rstd = rsqrtf(var + LN_EPS);

    const float4 g  = gammav[tid];
    const float4 bb = betav[tid];
    float4 o;
    o.x = (s.x - mu) * rstd * g.x + bb.x;
    o.y = (s.y - mu) * rstd * g.y + bb.y;
    o.z = (s.z - mu) * rstd * g.z + bb.z;
    o.w = (s.w - mu) * rstd * g.w + bb.w;
    outv[(size_t)b * D4 + tid] = o;
  }
}

extern "C" void kernel_launch(void* const* d_in, const int* in_sizes, int n_in,
                              void* d_out, int out_size, void* d_ws, size_t ws_size,
                              hipStream_t stream) {
  const float* ref_repr = (const float*)d_in[0];
  const float* alt_repr = (const float*)d_in[1];
  const int*   vpos     = (const int*)d_in[2];
  const float* gamma    = (const float*)d_in[3];
  const float* beta     = (const float*)d_in[4];
  float* out = (float*)d_out;

  fused_vdp_kernel<<<BATCH, NT, 0, stream>>>(
      (const float4*)ref_repr, (const float4*)alt_repr, vpos,
      (const float4*)gamma, (const float4*)beta, (float4*)out);
}